// Round 8
// baseline (180.885 us; speedup 1.0000x reference)
//
#include <hip/hip_runtime.h>

// Problem constants (fixed by setup_inputs): N=2048, B=64, H=W=4096, ks=8
#define GRIDN 64        // block positions per axis (H/B)
#define NCELLS 4096     // GRIDN*GRIDN
#define BVEC 8192       // float4 per block: 64*64*8/4
#define ROWSTRIDE4 8192 // float4 per dense row: W*ks/4

typedef float f32x4 __attribute__((ext_vector_type(4)));

// ---------------------------------------------------------------------------
// Single fused kernel, ONE WG PER CELL (round-8 delta): the per-wg index
// ballot-scan is paid once per cell instead of 4x (R6 had 4 chunk-wgs each
// rescanning all 16 KB of indices). The streaming body is looped over the 4
// chunks, instruction-identical per chunk to R6. Summation order (ascending
// n; per-chunk i-order) is unchanged => bit-identical output.
__global__ __launch_bounds__(256) void k_fused(const int* __restrict__ idxw,
                                               const f32x4* __restrict__ bv4,
                                               f32x4* __restrict__ out4,
                                               int N) {
    const int cell = blockIdx.x;
    const int R = cell >> 6;
    const int C = cell & (GRIDN - 1);
    const int tid = threadIdx.x;
    const int w = tid >> 6;
    const int lane = tid & 63;

    __shared__ unsigned long long masks[32];
    __shared__ short list_s[2048];
    __shared__ int odd_or;
    __shared__ int cnt_s;

    if (tid == 0) { odd_or = 0; cnt_s = 0; }
    __syncthreads();

    // ---- phase 1: int32 interpretation + dtype detect ----
    int my_or = 0;
#pragma unroll
    for (int k = 0; k < 8; ++k) {
        const int n = w * 512 + k * 64 + lane;
        int2 p = ((const int2*)idxw)[n];  // words 2n, 2n+1
        my_or |= p.y;                      // odd word
        const bool match = (n < N) && (p.x == R) && (p.y == C);
        unsigned long long mk = __ballot(match);
        if (lane == 0) masks[w * 8 + k] = mk;
    }
    if (__any(my_or != 0) && lane == 0) odd_or = 1;  // benign multi-write
    __syncthreads();

    if (odd_or == 0) {  // int64 indices: redo ballots from 16B entries
#pragma unroll
        for (int k = 0; k < 8; ++k) {
            const int n = w * 512 + k * 64 + lane;
            int4 p = ((const int4*)idxw)[n];  // words 4n..4n+3
            const bool match = (n < N) && (p.x == R) && (p.z == C);
            unsigned long long mk = __ballot(match);
            if (lane == 0) masks[w * 8 + k] = mk;
        }
        __syncthreads();
    }

    // ---- parallel ordered extraction (wave 0, lanes 0..31) ----
    if (tid < 64) {
        unsigned long long mk = (lane < 32) ? masks[lane] : 0ULL;
        const int pc = __popcll(mk);
        int pre = pc;  // inclusive prefix over lanes 0..31
#pragma unroll
        for (int d = 1; d < 32; d <<= 1) {
            int v = __shfl_up(pre, d, 64);
            if (lane >= d) pre += v;
        }
        int pos = pre - pc;  // exclusive
        const int base = lane * 64;
        while (mk) {
            const int b = __ffsll(mk) - 1;
            list_s[pos++] = (short)(base + b);
            mk &= mk - 1;
        }
        if (lane == 31) cnt_s = pre;
    }
    __syncthreads();
    const int cnt = cnt_s;

    // ---- streaming: loop 4 chunks, per-chunk body identical to R6 ----
    const size_t obase = (size_t)(R * 64) * ROWSTRIDE4 + (size_t)C * 128;

    if (cnt == 0) {
        const f32x4 z = {0.f, 0.f, 0.f, 0.f};
#pragma unroll 1
        for (int chunk = 0; chunk < 4; ++chunk) {
            const int tbase = chunk * 2048 + tid;
#pragma unroll
            for (int i = 0; i < 8; ++i) {
                int t = tbase + i * 256;
                __builtin_nontemporal_store(z, &out4[obase + (size_t)(t >> 7) * ROWSTRIDE4 + (t & 127)]);
            }
        }
    } else if (cnt == 1) {
        const f32x4* __restrict__ src = bv4 + (size_t)list_s[0] * BVEC;
#pragma unroll 1
        for (int chunk = 0; chunk < 4; ++chunk) {
            const int tbase = chunk * 2048 + tid;
#pragma unroll
            for (int i = 0; i < 8; ++i) {
                int t = tbase + i * 256;
                f32x4 v = __builtin_nontemporal_load(&src[t]);
                __builtin_nontemporal_store(v, &out4[obase + (size_t)(t >> 7) * ROWSTRIDE4 + (t & 127)]);
            }
        }
    } else {
#pragma unroll 1
        for (int chunk = 0; chunk < 4; ++chunk) {
            const int tbase = chunk * 2048 + tid;
            f32x4 acc[8];
#pragma unroll
            for (int i = 0; i < 8; ++i) acc[i] = (f32x4){0.f, 0.f, 0.f, 0.f};
            for (int j = 0; j < cnt; ++j) {
                const f32x4* __restrict__ src = bv4 + (size_t)list_s[j] * BVEC;
#pragma unroll
                for (int i = 0; i < 8; ++i)
                    acc[i] += __builtin_nontemporal_load(&src[tbase + i * 256]);
            }
#pragma unroll
            for (int i = 0; i < 8; ++i) {
                int t = tbase + i * 256;
                __builtin_nontemporal_store(acc[i], &out4[obase + (size_t)(t >> 7) * ROWSTRIDE4 + (t & 127)]);
            }
        }
    }
}

// ---------------------------------------------------------------------------
extern "C" void kernel_launch(void* const* d_in, const int* in_sizes, int n_in,
                              void* d_out, int out_size, void* d_ws, size_t ws_size,
                              hipStream_t stream) {
    const float* bv = (const float*)d_in[0];
    const int* idxw = (const int*)d_in[1];
    const int N = in_sizes[1] / 2;  // 2048 blocks

    k_fused<<<NCELLS, 256, 0, stream>>>(idxw, (const f32x4*)bv,
                                        (f32x4*)d_out, N);
}

// Round 9
// 153.089 us; speedup vs baseline: 1.1816x; 1.1816x over previous
//
#include <hip/hip_runtime.h>

// Problem constants (fixed by setup_inputs): N=2048, B=64, H=W=4096, ks=8
#define GRIDN 64        // block positions per axis (H/B)
#define NCELLS 4096     // GRIDN*GRIDN
#define BVEC 8192       // float4 per block: 64*64*8/4
#define ROWSTRIDE4 8192 // float4 per dense row: W*ks/4

typedef float f32x4 __attribute__((ext_vector_type(4)));

// ---------------------------------------------------------------------------
// Single fused kernel. Round-9 delta vs R6 (the 157.6 best): 512-thread wgs,
// grid 8192 = 4096 cells x 2 chunks. Per-thread streaming is bit-identical
// to R6 (acc[8], same t->(row,slot) map, ascending-j order => same output
// bits); the per-wg index ballot-scan now serves 64 KiB of streaming instead
// of 32 KiB (scan redundancy 4x -> 2x), ballots+barriers halved per byte.
// Occupancy: 8 waves/wg, 4 wgs/CU -> full 32 waves/CU; 8192 wgs = 32/CU for
// load balance.
__global__ __launch_bounds__(512) void k_fused(const int* __restrict__ idxw,
                                               const f32x4* __restrict__ bv4,
                                               f32x4* __restrict__ out4,
                                               int N) {
    const int cell = blockIdx.x >> 1;
    const int chunk = blockIdx.x & 1;
    const int R = cell >> 6;
    const int C = cell & (GRIDN - 1);
    const int tid = threadIdx.x;
    const int w = tid >> 6;      // wave 0..7
    const int lane = tid & 63;

    __shared__ unsigned long long masks[32];
    __shared__ short list_s[2048];
    __shared__ int odd_or;
    __shared__ int cnt_s;

    if (tid == 0) { odd_or = 0; cnt_s = 0; }
    __syncthreads();

    // ---- phase 1: int32 interpretation + dtype detect ----
    int my_or = 0;
#pragma unroll
    for (int k = 0; k < 4; ++k) {
        const int n = w * 256 + k * 64 + lane;
        int2 p = ((const int2*)idxw)[n];  // words 2n, 2n+1
        my_or |= p.y;                      // odd word
        const bool match = (n < N) && (p.x == R) && (p.y == C);
        unsigned long long mk = __ballot(match);
        if (lane == 0) masks[w * 4 + k] = mk;
    }
    if (__any(my_or != 0) && lane == 0) odd_or = 1;  // benign multi-write
    __syncthreads();

    if (odd_or == 0) {  // int64 indices: redo ballots from 16B entries
#pragma unroll
        for (int k = 0; k < 4; ++k) {
            const int n = w * 256 + k * 64 + lane;
            int4 p = ((const int4*)idxw)[n];  // words 4n..4n+3
            const bool match = (n < N) && (p.x == R) && (p.z == C);
            unsigned long long mk = __ballot(match);
            if (lane == 0) masks[w * 4 + k] = mk;
        }
        __syncthreads();
    }

    // ---- parallel ordered extraction (wave 0, lanes 0..31) ----
    if (tid < 64) {
        unsigned long long mk = (lane < 32) ? masks[lane] : 0ULL;
        const int pc = __popcll(mk);
        int pre = pc;  // inclusive prefix over lanes 0..31
#pragma unroll
        for (int d = 1; d < 32; d <<= 1) {
            int v = __shfl_up(pre, d, 64);
            if (lane >= d) pre += v;
        }
        int pos = pre - pc;  // exclusive
        const int base = lane * 64;
        while (mk) {
            const int b = __ffsll(mk) - 1;
            list_s[pos++] = (short)(base + b);
            mk &= mk - 1;
        }
        if (lane == 31) cnt_s = pre;
    }
    __syncthreads();
    const int cnt = cnt_s;

    // ---- streaming (per-thread identical to R6; tbase spans 4096/chunk) ----
    const int tbase = chunk * 4096 + tid;
    const size_t obase = (size_t)(R * 64) * ROWSTRIDE4 + (size_t)C * 128;

    if (cnt == 0) {
        const f32x4 z = {0.f, 0.f, 0.f, 0.f};
#pragma unroll
        for (int i = 0; i < 8; ++i) {
            int t = tbase + i * 512;
            __builtin_nontemporal_store(z, &out4[obase + (size_t)(t >> 7) * ROWSTRIDE4 + (t & 127)]);
        }
    } else if (cnt == 1) {
        const f32x4* __restrict__ src = bv4 + (size_t)list_s[0] * BVEC;
#pragma unroll
        for (int i = 0; i < 8; ++i) {
            int t = tbase + i * 512;
            f32x4 v = __builtin_nontemporal_load(&src[t]);
            __builtin_nontemporal_store(v, &out4[obase + (size_t)(t >> 7) * ROWSTRIDE4 + (t & 127)]);
        }
    } else {
        f32x4 acc[8];
#pragma unroll
        for (int i = 0; i < 8; ++i) acc[i] = (f32x4){0.f, 0.f, 0.f, 0.f};
        for (int j = 0; j < cnt; ++j) {
            const f32x4* __restrict__ src = bv4 + (size_t)list_s[j] * BVEC;
#pragma unroll
            for (int i = 0; i < 8; ++i)
                acc[i] += __builtin_nontemporal_load(&src[tbase + i * 512]);
        }
#pragma unroll
        for (int i = 0; i < 8; ++i) {
            int t = tbase + i * 512;
            __builtin_nontemporal_store(acc[i], &out4[obase + (size_t)(t >> 7) * ROWSTRIDE4 + (t & 127)]);
        }
    }
}

// ---------------------------------------------------------------------------
extern "C" void kernel_launch(void* const* d_in, const int* in_sizes, int n_in,
                              void* d_out, int out_size, void* d_ws, size_t ws_size,
                              hipStream_t stream) {
    const float* bv = (const float*)d_in[0];
    const int* idxw = (const int*)d_in[1];
    const int N = in_sizes[1] / 2;  // 2048 blocks

    k_fused<<<NCELLS * 2, 512, 0, stream>>>(idxw, (const f32x4*)bv,
                                            (f32x4*)d_out, N);
}